// Round 1
// baseline (2108.268 us; speedup 1.0000x reference)
//
#include <hip/hip_runtime.h>
#include <cstddef>

#define H 16
#define D 1024
#define DH 64
#define L 512

// ---------------- GEMM: Y = (X @ W + bias) * scale ----------------
// X: (M,K) row-major fp32, W: (K,N) row-major fp32, bias: (N)
// permute_head=1: write out[((b*H+h)*L+i)*DH+d] with b=m/L,i=m%L,h=n/DH,d=n%DH
// permute_head=0: write out[m*N+n]
#define TILE 64
#define BK 16

__global__ __launch_bounds__(256) void gemm_kernel(
    const float* __restrict__ X, const float* __restrict__ W,
    const float* __restrict__ bias, float* __restrict__ out,
    int M, int K, int N, float scale, int permute_head)
{
    __shared__ float As[BK][TILE];
    __shared__ float Bs[BK][TILE];
    const int tid = threadIdx.x;
    const int tx = tid & 15;        // 0..15 -> n
    const int ty = tid >> 4;        // 0..15 -> m
    const int m0 = blockIdx.y * TILE;
    const int n0 = blockIdx.x * TILE;

    const int arow = tid >> 2;          // 0..63
    const int acol = (tid & 3) * 4;     // 0,4,8,12
    const int brow = tid >> 4;          // 0..15
    const int bcol = (tid & 15) * 4;    // 0..60

    float acc[4][4];
    #pragma unroll
    for (int r = 0; r < 4; ++r)
        #pragma unroll
        for (int c = 0; c < 4; ++c) acc[r][c] = 0.f;

    for (int k0 = 0; k0 < K; k0 += BK) {
        float4 a4 = *(const float4*)(X + (size_t)(m0 + arow) * K + k0 + acol);
        float4 b4 = *(const float4*)(W + (size_t)(k0 + brow) * N + n0 + bcol);
        As[acol + 0][arow] = a4.x;
        As[acol + 1][arow] = a4.y;
        As[acol + 2][arow] = a4.z;
        As[acol + 3][arow] = a4.w;
        *(float4*)(&Bs[brow][bcol]) = b4;
        __syncthreads();
        #pragma unroll
        for (int kk = 0; kk < BK; ++kk) {
            float4 av = *(const float4*)(&As[kk][ty * 4]);
            float4 bv = *(const float4*)(&Bs[kk][tx * 4]);
            float a[4] = {av.x, av.y, av.z, av.w};
            float b[4] = {bv.x, bv.y, bv.z, bv.w};
            #pragma unroll
            for (int r = 0; r < 4; ++r)
                #pragma unroll
                for (int c = 0; c < 4; ++c)
                    acc[r][c] += a[r] * b[c];
        }
        __syncthreads();
    }

    #pragma unroll
    for (int r = 0; r < 4; ++r) {
        int m = m0 + ty * 4 + r;
        #pragma unroll
        for (int c = 0; c < 4; ++c) {
            int n = n0 + tx * 4 + c;
            float val = (acc[r][c] + bias[n]) * scale;
            if (permute_head) {
                int b = m >> 9;          // m / L
                int i = m & (L - 1);     // m % L
                int h = n >> 6;          // n / DH
                int d = n & (DH - 1);    // n % DH
                out[((((size_t)b * H + h) * L + i) * DH) + d] = val;
            } else {
                out[(size_t)m * N + n] = val;
            }
        }
    }
}

// ---------------- Attention: scores + softmax + context ----------------
// q,k,v: (B,H,L,DH).  mat: (B,L,L) int32.  mask: (B,1,L) bool (bytes).
// attn_out: (B,H,L,L).  ctx_out: (B,L,D) with ctx[b,i,h*DH+d].
__global__ __launch_bounds__(256) void attn_kernel(
    const float* __restrict__ q, const float* __restrict__ k,
    const float* __restrict__ v, const int* __restrict__ mat,
    const unsigned char* __restrict__ mask,
    const float* __restrict__ struct_emb, const float* __restrict__ value_emb,
    float* __restrict__ attn_out, float* __restrict__ ctx_out)
{
    const int i = blockIdx.x;
    const int h = blockIdx.y;
    const int b = blockIdx.z;
    const int tid = threadIdx.x;

    __shared__ float qv[DH];
    __shared__ float sc[L];
    __shared__ float red[256];

    const float* qptr = q + ((((size_t)b * H + h) * L + i) * DH);
    if (tid < DH) qv[tid] = qptr[tid];
    __syncthreads();

    const float* kbase = k + (((size_t)b * H + h) * L) * DH;
    const int* mrow = mat + ((size_t)b * L + i) * L;

    // scores: s = q . (k + pe)
    for (int j = tid; j < L; j += 256) {
        const float* krow = kbase + (size_t)j * DH;
        int idx = mrow[j];
        const float* erow = ((j & 1) ? value_emb : struct_emb) + (size_t)idx * DH;
        float s = 0.f;
        #pragma unroll
        for (int d4 = 0; d4 < DH; d4 += 4) {
            float4 kk4 = *(const float4*)(krow + d4);
            float4 ee4 = *(const float4*)(erow + d4);
            s += qv[d4 + 0] * (kk4.x + ee4.x);
            s += qv[d4 + 1] * (kk4.y + ee4.y);
            s += qv[d4 + 2] * (kk4.z + ee4.z);
            s += qv[d4 + 3] * (kk4.w + ee4.w);
        }
        if (mask[(size_t)b * L + j]) s = -1e18f;
        sc[j] = s;
    }
    __syncthreads();

    // max-reduce
    float m = -3.0e38f;
    for (int j = tid; j < L; j += 256) m = fmaxf(m, sc[j]);
    red[tid] = m;
    __syncthreads();
    for (int s = 128; s > 0; s >>= 1) {
        if (tid < s) red[tid] = fmaxf(red[tid], red[tid + s]);
        __syncthreads();
    }
    float mx = red[0];
    __syncthreads();

    // exp + sum-reduce
    float sum = 0.f;
    for (int j = tid; j < L; j += 256) {
        float e = expf(sc[j] - mx);
        sc[j] = e;
        sum += e;
    }
    red[tid] = sum;
    __syncthreads();
    for (int s = 128; s > 0; s >>= 1) {
        if (tid < s) red[tid] += red[tid + s];
        __syncthreads();
    }
    float inv = 1.f / red[0];
    __syncthreads();

    // normalize + write attn row
    float* arow_p = attn_out + ((((size_t)b * H + h) * L + i) * L);
    for (int j = tid; j < L; j += 256) {
        float p = sc[j] * inv;
        sc[j] = p;
        arow_p[j] = p;
    }
    __syncthreads();

    // context: ctx[d] = sum_j p[j] * v[j][d]
    const int d = tid & 63;
    const int g = tid >> 6;   // 4 groups
    const float* vbase = v + (((size_t)b * H + h) * L) * DH;
    float acc = 0.f;
    for (int j = g; j < L; j += 4) acc += sc[j] * vbase[(size_t)j * DH + d];
    red[tid] = acc;
    __syncthreads();
    if (tid < 64) {
        float c = red[tid] + red[64 + tid] + red[128 + tid] + red[192 + tid];
        ctx_out[((size_t)b * L + i) * D + h * DH + tid] = c;
    }
}

extern "C" void kernel_launch(void* const* d_in, const int* in_sizes, int n_in,
                              void* d_out, int out_size, void* d_ws, size_t ws_size,
                              hipStream_t stream) {
    const float* key_in   = (const float*)d_in[0];
    const float* value_in = (const float*)d_in[1];
    const float* query_in = (const float*)d_in[2];
    const int*   mat      = (const int*)d_in[3];
    const unsigned char* mask = (const unsigned char*)d_in[4];
    const float* Wq = (const float*)d_in[5];
    const float* bq = (const float*)d_in[6];
    const float* Wk = (const float*)d_in[7];
    const float* bk = (const float*)d_in[8];
    const float* Wv = (const float*)d_in[9];
    const float* bv = (const float*)d_in[10];
    const float* Wo = (const float*)d_in[11];
    const float* bo = (const float*)d_in[12];
    const float* struct_emb = (const float*)d_in[13];
    const float* value_emb  = (const float*)d_in[14];

    const int B = in_sizes[2] / (L * D);   // 4
    const int M = B * L;                   // 2048

    float* ws  = (float*)d_ws;
    float* qws = ws;
    float* kws = qws + (size_t)M * D;
    float* vws = kws + (size_t)M * D;
    float* cws = vws + (size_t)M * D;

    float* out_p  = (float*)d_out;
    float* attn_p = out_p + (size_t)M * D;

    dim3 gblock(256);
    dim3 ggrid(D / TILE, M / TILE);

    gemm_kernel<<<ggrid, gblock, 0, stream>>>(query_in, Wq, bq, qws, M, D, D, 0.125f, 1);
    gemm_kernel<<<ggrid, gblock, 0, stream>>>(key_in,   Wk, bk, kws, M, D, D, 1.0f,   1);
    gemm_kernel<<<ggrid, gblock, 0, stream>>>(value_in, Wv, bv, vws, M, D, D, 1.0f,   1);

    attn_kernel<<<dim3(L, H, B), dim3(256), 0, stream>>>(
        qws, kws, vws, mat, mask, struct_emb, value_emb, attn_p, cws);

    gemm_kernel<<<ggrid, gblock, 0, stream>>>(cws, Wo, bo, out_p, M, D, D, 1.0f, 0);
}

// Round 2
// 576.393 us; speedup vs baseline: 3.6577x; 3.6577x over previous
//
#include <hip/hip_runtime.h>
#include <hip/hip_bf16.h>
#include <cstddef>

#define H 16
#define D 1024
#define DH 64
#define L 512

typedef __attribute__((ext_vector_type(8))) short bf16x8;
typedef __attribute__((ext_vector_type(4))) float f32x4;

__device__ inline short f2bf(float x) {
    union { float f; unsigned u; } c; c.f = x;
    unsigned r = (c.u + 0x7FFFu + ((c.u >> 16) & 1u)) >> 16;
    return (short)r;
}

// ---------------- GEMM: Y = (X @ W + bias) * scale ----------------
// out_mode: 0 = fp32 row-major (M,N); 1 = fp32 permuted (B,H,L,DH); 2 = bf16 permuted
#define TILE 64
#define BK 16

__global__ __launch_bounds__(256) void gemm_kernel(
    const float* __restrict__ X, const float* __restrict__ W,
    const float* __restrict__ bias, void* __restrict__ out,
    int M, int K, int N, float scale, int out_mode)
{
    __shared__ float As[BK][TILE];
    __shared__ float Bs[BK][TILE];
    const int tid = threadIdx.x;
    const int tx = tid & 15;
    const int ty = tid >> 4;
    const int m0 = blockIdx.y * TILE;
    const int n0 = blockIdx.x * TILE;

    const int arow = tid >> 2;
    const int acol = (tid & 3) * 4;
    const int brow = tid >> 4;
    const int bcol = (tid & 15) * 4;

    float acc[4][4];
    #pragma unroll
    for (int r = 0; r < 4; ++r)
        #pragma unroll
        for (int c = 0; c < 4; ++c) acc[r][c] = 0.f;

    for (int k0 = 0; k0 < K; k0 += BK) {
        float4 a4 = *(const float4*)(X + (size_t)(m0 + arow) * K + k0 + acol);
        float4 b4 = *(const float4*)(W + (size_t)(k0 + brow) * N + n0 + bcol);
        As[acol + 0][arow] = a4.x;
        As[acol + 1][arow] = a4.y;
        As[acol + 2][arow] = a4.z;
        As[acol + 3][arow] = a4.w;
        *(float4*)(&Bs[brow][bcol]) = b4;
        __syncthreads();
        #pragma unroll
        for (int kk = 0; kk < BK; ++kk) {
            float4 av = *(const float4*)(&As[kk][ty * 4]);
            float4 bv = *(const float4*)(&Bs[kk][tx * 4]);
            float a[4] = {av.x, av.y, av.z, av.w};
            float b[4] = {bv.x, bv.y, bv.z, bv.w};
            #pragma unroll
            for (int r = 0; r < 4; ++r)
                #pragma unroll
                for (int c = 0; c < 4; ++c)
                    acc[r][c] += a[r] * b[c];
        }
        __syncthreads();
    }

    #pragma unroll
    for (int r = 0; r < 4; ++r) {
        int m = m0 + ty * 4 + r;
        #pragma unroll
        for (int c = 0; c < 4; ++c) {
            int n = n0 + tx * 4 + c;
            float val = (acc[r][c] + bias[n]) * scale;
            if (out_mode == 0) {
                ((float*)out)[(size_t)m * N + n] = val;
            } else {
                int b = m >> 9;          // m / L
                int i = m & (L - 1);     // m % L
                int h = n >> 6;          // n / DH
                int d = n & (DH - 1);    // n % DH
                size_t pidx = ((((size_t)b * H + h) * L + i) * DH) + d;
                if (out_mode == 1) ((float*)out)[pidx] = val;
                else               ((short*)out)[pidx] = f2bf(val);
            }
        }
    }
}

// ---------------- qk scores: S[b,h,i,j] = Q_bh . K_bh^T (MFMA bf16) ----------------
// grid (L/64 j-blocks, L/64 i-blocks, B*H); block 256 = 4 waves.
// wave w handles i-rows [w*16, w*16+16) x 64 j.
__global__ __launch_bounds__(256) void qk_kernel(
    const short* __restrict__ Qb16, const short* __restrict__ Kb16,
    float* __restrict__ S)
{
    const int bh   = blockIdx.z;
    const int wave = threadIdx.x >> 6;
    const int lane = threadIdx.x & 63;
    const int m    = lane & 15;
    const int quad = lane >> 4;
    const int i0   = blockIdx.y * 64 + wave * 16;
    const int j0   = blockIdx.x * 64;

    const short* Q = Qb16 + (size_t)bh * L * DH;
    const short* K = Kb16 + (size_t)bh * L * DH;

    // A fragment: A[m][k] = Q[i0+m][k], k = quad*8 + jj (+32 for chunk 1)
    bf16x8 a0 = *(const bf16x8*)(Q + (size_t)(i0 + m) * DH + quad * 8);
    bf16x8 a1 = *(const bf16x8*)(Q + (size_t)(i0 + m) * DH + 32 + quad * 8);

    f32x4 acc[4];
    #pragma unroll
    for (int jt = 0; jt < 4; ++jt) {
        // B fragment: B[k][n] = K[j0+jt*16+n][k]  (n = lane&15)
        const short* Krow = K + (size_t)(j0 + jt * 16 + m) * DH + quad * 8;
        bf16x8 b0 = *(const bf16x8*)(Krow);
        bf16x8 b1 = *(const bf16x8*)(Krow + 32);
        f32x4 c = {0.f, 0.f, 0.f, 0.f};
        c = __builtin_amdgcn_mfma_f32_16x16x32_bf16(a0, b0, c, 0, 0, 0);
        c = __builtin_amdgcn_mfma_f32_16x16x32_bf16(a1, b1, c, 0, 0, 0);
        acc[jt] = c;
    }

    float* Sb = S + (size_t)bh * L * L;
    #pragma unroll
    for (int jt = 0; jt < 4; ++jt)
        #pragma unroll
        for (int r = 0; r < 4; ++r)
            Sb[(size_t)(i0 + quad * 4 + r) * L + j0 + jt * 16 + m] = acc[jt][r];
}

// ---------------- ast scores: S[b,h,i,j] += Q[b,:,i,:] . PE[b,i,j,:] ----------------
// One block per (b,i): A = Q all-heads (16h x 64d), B = PE^T (64d x 512j).
// Emb gather done ONCE per (b,i,j) and shared across all 16 heads via MFMA.
// grid (L, B); block 256 = 4 waves; wave w handles j-tiles w, w+4, ...
__global__ __launch_bounds__(256) void ast_kernel(
    const short* __restrict__ Qb16, const int* __restrict__ mat,
    const float* __restrict__ struct_emb, const float* __restrict__ value_emb,
    float* __restrict__ S)
{
    const int i    = blockIdx.x;
    const int b    = blockIdx.y;
    const int wave = threadIdx.x >> 6;
    const int lane = threadIdx.x & 63;
    const int n    = lane & 15;   // h for A-load, j-offset for B-load
    const int quad = lane >> 4;

    // A fragment: A[m=h][k=d], m = lane&15
    const size_t qbase = ((size_t)(b * H + n) * L + i) * DH;
    bf16x8 a0 = *(const bf16x8*)(Qb16 + qbase + quad * 8);
    bf16x8 a1 = *(const bf16x8*)(Qb16 + qbase + 32 + quad * 8);

    const int* mrow = mat + ((size_t)b * L + i) * L;

    for (int jt = wave; jt < L / 16; jt += 4) {
        const int j = jt * 16 + n;
        const int idx = mrow[j];
        const float* er = ((j & 1) ? value_emb : struct_emb) + (size_t)idx * DH;
        // B fragment: B[k][n] = pe[j][k]; load 8 fp32, cvt to bf16
        float4 e0a = *(const float4*)(er + quad * 8);
        float4 e0b = *(const float4*)(er + quad * 8 + 4);
        float4 e1a = *(const float4*)(er + 32 + quad * 8);
        float4 e1b = *(const float4*)(er + 32 + quad * 8 + 4);
        bf16x8 b0, b1;
        b0[0] = f2bf(e0a.x); b0[1] = f2bf(e0a.y); b0[2] = f2bf(e0a.z); b0[3] = f2bf(e0a.w);
        b0[4] = f2bf(e0b.x); b0[5] = f2bf(e0b.y); b0[6] = f2bf(e0b.z); b0[7] = f2bf(e0b.w);
        b1[0] = f2bf(e1a.x); b1[1] = f2bf(e1a.y); b1[2] = f2bf(e1a.z); b1[3] = f2bf(e1a.w);
        b1[4] = f2bf(e1b.x); b1[5] = f2bf(e1b.y); b1[6] = f2bf(e1b.z); b1[7] = f2bf(e1b.w);
        f32x4 acc = {0.f, 0.f, 0.f, 0.f};
        acc = __builtin_amdgcn_mfma_f32_16x16x32_bf16(a0, b0, acc, 0, 0, 0);
        acc = __builtin_amdgcn_mfma_f32_16x16x32_bf16(a1, b1, acc, 0, 0, 0);
        // D[m=h][n=j]: h = quad*4 + r, accumulate into S
        #pragma unroll
        for (int r = 0; r < 4; ++r) {
            int h = quad * 4 + r;
            float* sp = S + (((size_t)(b * H + h) * L + i) * L) + j;
            *sp += acc[r];
        }
    }
}

// ---------------- softmax + PV ----------------
// grid (L/16, H, B); block 256. Reads S (fp32), applies mask, row-softmax,
// writes normalized attn back, computes context = P @ V (fp32 VALU).
__global__ __launch_bounds__(256) void softmax_pv_kernel(
    float* __restrict__ S, const float* __restrict__ V,
    const unsigned char* __restrict__ mask, float* __restrict__ ctx)
{
    const int i0 = blockIdx.x * 16;
    const int h  = blockIdx.y;
    const int b  = blockIdx.z;
    const int tid = threadIdx.x;

    __shared__ float P[16][L];   // 32 KB

    const size_t base = ((size_t)(b * H + h) * L + i0) * L;

    // load + mask
    for (int idx = tid; idx < 16 * (L / 4); idx += 256) {
        int r  = idx >> 7;          // /128
        int c4 = (idx & 127) << 2;  // *4
        float4 s4 = *(const float4*)(S + base + (size_t)r * L + c4);
        if (mask[(size_t)b * L + c4 + 0]) s4.x = -1e18f;
        if (mask[(size_t)b * L + c4 + 1]) s4.y = -1e18f;
        if (mask[(size_t)b * L + c4 + 2]) s4.z = -1e18f;
        if (mask[(size_t)b * L + c4 + 3]) s4.w = -1e18f;
        *(float4*)(&P[r][c4]) = s4;
    }
    __syncthreads();

    // per-row softmax: wave w handles rows w*4 .. w*4+3
    const int wave = tid >> 6;
    const int lane = tid & 63;
    for (int rr = 0; rr < 4; ++rr) {
        int r = wave * 4 + rr;
        float mx = -3.0e38f;
        for (int j = lane; j < L; j += 64) mx = fmaxf(mx, P[r][j]);
        #pragma unroll
        for (int off = 32; off > 0; off >>= 1) mx = fmaxf(mx, __shfl_xor(mx, off));
        float sum = 0.f;
        for (int j = lane; j < L; j += 64) {
            float e = __expf(P[r][j] - mx);
            P[r][j] = e;
            sum += e;
        }
        #pragma unroll
        for (int off = 32; off > 0; off >>= 1) sum += __shfl_xor(sum, off);
        float inv = 1.f / sum;
        for (int j = lane; j < L; j += 64) {
            float p = P[r][j] * inv;
            P[r][j] = p;
            S[base + (size_t)r * L + j] = p;
        }
    }
    __syncthreads();

    // PV: group g (of 4) handles rows g*4..g*4+3; thread owns one d
    const int d = tid & 63;
    const int g = tid >> 6;
    const float* Vb = V + ((size_t)(b * H + h) * L) * DH;
    float acc[4] = {0.f, 0.f, 0.f, 0.f};
    #pragma unroll 4
    for (int j = 0; j < L; ++j) {
        float v = Vb[(size_t)j * DH + d];
        #pragma unroll
        for (int ii = 0; ii < 4; ++ii) acc[ii] += P[g * 4 + ii][j] * v;
    }
    #pragma unroll
    for (int ii = 0; ii < 4; ++ii) {
        int i = i0 + g * 4 + ii;
        ctx[((size_t)b * L + i) * D + h * DH + d] = acc[ii];
    }
}

extern "C" void kernel_launch(void* const* d_in, const int* in_sizes, int n_in,
                              void* d_out, int out_size, void* d_ws, size_t ws_size,
                              hipStream_t stream) {
    const float* key_in   = (const float*)d_in[0];
    const float* value_in = (const float*)d_in[1];
    const float* query_in = (const float*)d_in[2];
    const int*   mat      = (const int*)d_in[3];
    const unsigned char* mask = (const unsigned char*)d_in[4];
    const float* Wq = (const float*)d_in[5];
    const float* bq = (const float*)d_in[6];
    const float* Wk = (const float*)d_in[7];
    const float* bk = (const float*)d_in[8];
    const float* Wv = (const float*)d_in[9];
    const float* bv = (const float*)d_in[10];
    const float* Wo = (const float*)d_in[11];
    const float* bo = (const float*)d_in[12];
    const float* struct_emb = (const float*)d_in[13];
    const float* value_emb  = (const float*)d_in[14];

    const int B = in_sizes[2] / (L * D);   // 4
    const int M = B * L;                   // 2048

    short* qbf = (short*)d_ws;
    short* kbf = qbf + (size_t)M * D;
    float* vws = (float*)(kbf + (size_t)M * D);
    float* cws = vws + (size_t)M * D;

    float* out_p  = (float*)d_out;
    float* attn_p = out_p + (size_t)M * D;   // scores scratch, then attn output

    dim3 gblock(256);
    dim3 ggrid(D / TILE, M / TILE);

    gemm_kernel<<<ggrid, gblock, 0, stream>>>(query_in, Wq, bq, qbf, M, D, D, 0.125f, 2);
    gemm_kernel<<<ggrid, gblock, 0, stream>>>(key_in,   Wk, bk, kbf, M, D, D, 1.0f,   2);
    gemm_kernel<<<ggrid, gblock, 0, stream>>>(value_in, Wv, bv, vws, M, D, D, 1.0f,   1);

    qk_kernel<<<dim3(L / 64, L / 64, B * H), gblock, 0, stream>>>(qbf, kbf, attn_p);
    ast_kernel<<<dim3(L, B), gblock, 0, stream>>>(qbf, mat, struct_emb, value_emb, attn_p);
    softmax_pv_kernel<<<dim3(L / 16, H, B), gblock, 0, stream>>>(attn_p, vws, mask, cws);

    gemm_kernel<<<ggrid, gblock, 0, stream>>>(cws, Wo, bo, out_p, M, D, D, 1.0f, 0);
}

// Round 3
// 293.965 us; speedup vs baseline: 7.1718x; 1.9608x over previous
//
#include <hip/hip_runtime.h>
#include <cstddef>

#define H 16
#define D 1024
#define DH 64
#define L 512

typedef __attribute__((ext_vector_type(8))) short bf16x8;
typedef __attribute__((ext_vector_type(4))) short bf16x4;
typedef __attribute__((ext_vector_type(4))) float f32x4;

__device__ inline short f2bf(float x) {
    union { float f; unsigned u; } c; c.f = x;
    unsigned r = (c.u + 0x7FFFu + ((c.u >> 16) & 1u)) >> 16;
    return (short)r;
}
__device__ inline float bf2f(short x) {
    union { float f; unsigned u; } c;
    c.u = ((unsigned)(unsigned short)x) << 16; return c.f;
}

// ---------------- fp32 -> bf16 convert (multi-region) ----------------
struct CvtArgs { const float* src[5]; short* dst[5]; int n[5]; };

__global__ __launch_bounds__(256) void cvt_kernel(CvtArgs a) {
    int r = blockIdx.y;
    const float* s = a.src[r];
    short* d = a.dst[r];
    int n = a.n[r];
    int i = (blockIdx.x * 256 + threadIdx.x) * 8;
    if (i >= n) return;
    float4 x0 = *(const float4*)(s + i);
    float4 x1 = *(const float4*)(s + i + 4);
    bf16x8 o;
    o[0] = f2bf(x0.x); o[1] = f2bf(x0.y); o[2] = f2bf(x0.z); o[3] = f2bf(x0.w);
    o[4] = f2bf(x1.x); o[5] = f2bf(x1.y); o[6] = f2bf(x1.z); o[7] = f2bf(x1.w);
    *(bf16x8*)(d + i) = o;
}

// ---------------- weight transpose+convert: W (K x N) fp32 -> W^T (N x K) bf16 ----------------
struct WtArgs { const float* W[4]; short* T[4]; };

__global__ __launch_bounds__(256) void wtrans_kernel(WtArgs a) {
    const float* W = a.W[blockIdx.z];
    short* T = a.T[blockIdx.z];
    int idx = blockIdx.x * 256 + threadIdx.x;
    int n = idx & 1023;
    int k0 = (idx >> 10) << 3;
    bf16x8 o;
    #pragma unroll
    for (int kk = 0; kk < 8; ++kk)
        o[kk] = f2bf(W[(size_t)(k0 + kk) * 1024 + n]);   // coalesced across lanes (n contiguous)
    *(bf16x8*)(T + (size_t)n * 1024 + k0) = o;
}

// ---------------- MFMA GEMM: C = (A @ Bt^T + bias) * scale ----------------
// A: (M,K) bf16 row-major. Bt: (N,K) bf16 row-major (i.e. W^T). bias fp32.
// mode 0: fp32 flat [m][n]; mode 1: bf16 (B,H,L,DH); mode 2: bf16 (B,H,DH,L)
#define BM 128
#define BN 64
#define BKK 64

__global__ __launch_bounds__(256) void gemm_bf16_kernel(
    const short* __restrict__ A, const short* __restrict__ Bt,
    const float* __restrict__ bias, void* __restrict__ out,
    int M, int N, int K, float scale, int mode)
{
    __shared__ short As[BM][BKK + 8];
    __shared__ short Bs[BN][BKK + 8];
    const int tid = threadIdx.x;
    const int m0 = blockIdx.y * BM;
    const int n0 = blockIdx.x * BN;
    const int wave = tid >> 6, lane = tid & 63;
    const int fm = lane & 15, quad = lane >> 4;

    const int ar = tid >> 1, ah = (tid & 1) * 32;   // A staging: row, col-half
    const int br = tid >> 2, bq = (tid & 3) * 16;   // B staging: row, col-quarter

    f32x4 acc[2][4];
    #pragma unroll
    for (int mt = 0; mt < 2; ++mt)
        #pragma unroll
        for (int nt = 0; nt < 4; ++nt) acc[mt][nt] = (f32x4){0.f, 0.f, 0.f, 0.f};

    const short* Ag = A + (size_t)(m0 + ar) * K + ah;
    const short* Bg = Bt + (size_t)(n0 + br) * K + bq;

    for (int k0 = 0; k0 < K; k0 += BKK) {
        bf16x8 a0 = *(const bf16x8*)(Ag + k0);
        bf16x8 a1 = *(const bf16x8*)(Ag + k0 + 8);
        bf16x8 a2 = *(const bf16x8*)(Ag + k0 + 16);
        bf16x8 a3 = *(const bf16x8*)(Ag + k0 + 24);
        bf16x8 b0 = *(const bf16x8*)(Bg + k0);
        bf16x8 b1 = *(const bf16x8*)(Bg + k0 + 8);
        __syncthreads();   // prior iter's fragment reads done before overwrite
        *(bf16x8*)(&As[ar][ah])      = a0;
        *(bf16x8*)(&As[ar][ah + 8])  = a1;
        *(bf16x8*)(&As[ar][ah + 16]) = a2;
        *(bf16x8*)(&As[ar][ah + 24]) = a3;
        *(bf16x8*)(&Bs[br][bq])      = b0;
        *(bf16x8*)(&Bs[br][bq + 8])  = b1;
        __syncthreads();
        #pragma unroll
        for (int ks = 0; ks < BKK; ks += 32) {
            bf16x8 af[2], bfr[4];
            af[0] = *(const bf16x8*)(&As[wave * 32 + fm][ks + quad * 8]);
            af[1] = *(const bf16x8*)(&As[wave * 32 + 16 + fm][ks + quad * 8]);
            #pragma unroll
            for (int nt = 0; nt < 4; ++nt)
                bfr[nt] = *(const bf16x8*)(&Bs[nt * 16 + fm][ks + quad * 8]);
            #pragma unroll
            for (int mt = 0; mt < 2; ++mt)
                #pragma unroll
                for (int nt = 0; nt < 4; ++nt)
                    acc[mt][nt] = __builtin_amdgcn_mfma_f32_16x16x32_bf16(
                        af[mt], bfr[nt], acc[mt][nt], 0, 0, 0);
        }
    }

    if (mode == 2) {
        // transpose tile in LDS so (d, i) stores are vectorized
        __syncthreads();
        short (*T)[BM + 8] = (short(*)[BM + 8])&As[0][0];  // 64 x 136 shorts, fits in As
        #pragma unroll
        for (int mt = 0; mt < 2; ++mt)
            #pragma unroll
            for (int nt = 0; nt < 4; ++nt) {
                int nn = nt * 16 + fm;
                float bv = bias[n0 + nn];
                #pragma unroll
                for (int r = 0; r < 4; ++r) {
                    int mm = wave * 32 + mt * 16 + quad * 4 + r;
                    T[nn][mm] = f2bf((acc[mt][nt][r] + bv) * scale);
                }
            }
        __syncthreads();
        int b = m0 >> 9;
        int ibase = m0 & (L - 1);
        int hblk = n0 >> 6;
        int n = tid >> 2, seg = (tid & 3) * 32;
        short* dst = (short*)out + (((size_t)(b * H + hblk) * DH + n) * L) + ibase + seg;
        #pragma unroll
        for (int c = 0; c < 4; ++c)
            *(bf16x8*)(dst + c * 8) = *(const bf16x8*)(&T[n][seg + c * 8]);
    } else {
        #pragma unroll
        for (int mt = 0; mt < 2; ++mt)
            #pragma unroll
            for (int nt = 0; nt < 4; ++nt) {
                int n = n0 + nt * 16 + fm;
                float bv = bias[n];
                #pragma unroll
                for (int r = 0; r < 4; ++r) {
                    int m = m0 + wave * 32 + mt * 16 + quad * 4 + r;
                    float val = (acc[mt][nt][r] + bv) * scale;
                    if (mode == 0) {
                        ((float*)out)[(size_t)m * N + n] = val;
                    } else {
                        int b = m >> 9, i = m & (L - 1);
                        int h = n >> 6, d = n & (DH - 1);
                        ((short*)out)[(((size_t)(b * H + h) * L + i) * DH) + d] = f2bf(val);
                    }
                }
            }
    }
}

// ---------------- ast scores -> Sast bf16 [b][i][h][j] ----------------
__global__ __launch_bounds__(256) void ast_kernel(
    const short* __restrict__ Qb, const int* __restrict__ mat,
    const short* __restrict__ semb, const short* __restrict__ vemb,
    short* __restrict__ Sast)
{
    const int i = blockIdx.x, b = blockIdx.y;
    const int tid = threadIdx.x;
    const int wave = tid >> 6, lane = tid & 63;
    const int fm = lane & 15, quad = lane >> 4;
    __shared__ short Sl[H][L + 8];

    // A[m=h][k=d] = Q[b, h, i, d]
    const short* qp = Qb + (((size_t)(b * H + fm) * L + i) * DH);
    bf16x8 a0 = *(const bf16x8*)(qp + quad * 8);
    bf16x8 a1 = *(const bf16x8*)(qp + 32 + quad * 8);

    const int* mrow = mat + ((size_t)b * L + i) * L;

    for (int jt = wave; jt < L / 16; jt += 4) {
        int j = jt * 16 + fm;
        int idx = mrow[j];
        const short* er = ((j & 1) ? vemb : semb) + (size_t)idx * DH;
        bf16x8 b0 = *(const bf16x8*)(er + quad * 8);
        bf16x8 b1 = *(const bf16x8*)(er + 32 + quad * 8);
        f32x4 c = {0.f, 0.f, 0.f, 0.f};
        c = __builtin_amdgcn_mfma_f32_16x16x32_bf16(a0, b0, c, 0, 0, 0);
        c = __builtin_amdgcn_mfma_f32_16x16x32_bf16(a1, b1, c, 0, 0, 0);
        #pragma unroll
        for (int r = 0; r < 4; ++r)
            Sl[quad * 4 + r][j] = f2bf(c[r]);   // row = h, col = j
    }
    __syncthreads();
    int hh = tid >> 4, j0 = (tid & 15) * 32;
    short* dst = Sast + ((((size_t)b * L + i) * H + hh) * L) + j0;
    #pragma unroll
    for (int c = 0; c < 4; ++c)
        *(bf16x8*)(dst + c * 8) = *(const bf16x8*)(&Sl[hh][j0 + c * 8]);
}

// ---------------- fused qk + ast-add + softmax + PV ----------------
// block = (i-tile of 16, h, b). Writes attn fp32 and ctx bf16 (B,L,D).
__global__ __launch_bounds__(256) void attn_fused_kernel(
    const short* __restrict__ Qb, const short* __restrict__ Kb,
    const short* __restrict__ Vt, const short* __restrict__ Sast,
    const unsigned char* __restrict__ mask,
    float* __restrict__ attn, short* __restrict__ ctx)
{
    const int i0 = blockIdx.x * 16;
    const int h = blockIdx.y;
    const int b = blockIdx.z;
    const int tid = threadIdx.x;
    const int wave = tid >> 6, lane = tid & 63;
    const int fm = lane & 15, quad = lane >> 4;

    __shared__ float S[16][L + 4];    // scores fp32
    __shared__ short Pb[16][L + 8];   // Sast staging, then P bf16

    // stage Sast tile -> Pb
    {
        int r = tid >> 4, c0 = (tid & 15) * 32;
        const short* sp = Sast + ((((size_t)b * L + i0 + r) * H + h) * L) + c0;
        #pragma unroll
        for (int c = 0; c < 4; ++c)
            *(bf16x8*)(&Pb[r][c0 + c * 8]) = *(const bf16x8*)(sp + c * 8);
    }
    __syncthreads();

    // qk via MFMA, K fragments streamed from global (L2)
    const short* qp = Qb + (((size_t)(b * H + h) * L + i0 + fm) * DH);
    bf16x8 a0 = *(const bf16x8*)(qp + quad * 8);
    bf16x8 a1 = *(const bf16x8*)(qp + 32 + quad * 8);
    const short* Kbase = Kb + ((size_t)(b * H + h) * L) * DH;

    for (int jt = wave; jt < L / 16; jt += 4) {
        int j = jt * 16 + fm;
        const short* kr = Kbase + (size_t)j * DH;
        bf16x8 b0 = *(const bf16x8*)(kr + quad * 8);
        bf16x8 b1 = *(const bf16x8*)(kr + 32 + quad * 8);
        f32x4 c = {0.f, 0.f, 0.f, 0.f};
        c = __builtin_amdgcn_mfma_f32_16x16x32_bf16(a0, b0, c, 0, 0, 0);
        c = __builtin_amdgcn_mfma_f32_16x16x32_bf16(a1, b1, c, 0, 0, 0);
        bool mk = mask[(size_t)b * L + j] != 0;
        #pragma unroll
        for (int r = 0; r < 4; ++r) {
            int ir = quad * 4 + r;
            S[ir][j] = mk ? -1e18f : (c[r] + bf2f(Pb[ir][j]));
        }
    }
    __syncthreads();

    // softmax: wave owns rows wave*4 .. wave*4+3
    #pragma unroll
    for (int rr = 0; rr < 4; ++rr) {
        int r = wave * 4 + rr;
        float mx = -3.0e38f;
        #pragma unroll
        for (int it = 0; it < 2; ++it) {
            float4 v = *(const float4*)(&S[r][lane * 4 + it * 256]);
            mx = fmaxf(mx, fmaxf(fmaxf(v.x, v.y), fmaxf(v.z, v.w)));
        }
        #pragma unroll
        for (int off = 32; off > 0; off >>= 1) mx = fmaxf(mx, __shfl_xor(mx, off));
        float sum = 0.f;
        #pragma unroll
        for (int it = 0; it < 2; ++it) {
            float4 v = *(const float4*)(&S[r][lane * 4 + it * 256]);
            v.x = __expf(v.x - mx); v.y = __expf(v.y - mx);
            v.z = __expf(v.z - mx); v.w = __expf(v.w - mx);
            *(float4*)(&S[r][lane * 4 + it * 256]) = v;
            sum += v.x + v.y + v.z + v.w;
        }
        #pragma unroll
        for (int off = 32; off > 0; off >>= 1) sum += __shfl_xor(sum, off);
        float inv = 1.f / sum;
        float* arow = attn + (((size_t)(b * H + h) * L + i0 + r) * L);
        #pragma unroll
        for (int it = 0; it < 2; ++it) {
            int j4 = lane * 4 + it * 256;
            float4 v = *(const float4*)(&S[r][j4]);
            v.x *= inv; v.y *= inv; v.z *= inv; v.w *= inv;
            *(float4*)(arow + j4) = v;
            bf16x4 pk;
            pk[0] = f2bf(v.x); pk[1] = f2bf(v.y); pk[2] = f2bf(v.z); pk[3] = f2bf(v.w);
            *(bf16x4*)(&Pb[r][j4]) = pk;
        }
    }
    __syncthreads();

    // PV via MFMA: wave owns d-tile [wave*16, wave*16+16)
    const short* Vb = Vt + (((size_t)(b * H + h) * DH + wave * 16 + fm) * L);
    f32x4 o = {0.f, 0.f, 0.f, 0.f};
    for (int ks = 0; ks < L; ks += 32) {
        bf16x8 pa = *(const bf16x8*)(&Pb[fm][ks + quad * 8]);
        bf16x8 vb = *(const bf16x8*)(Vb + ks + quad * 8);
        o = __builtin_amdgcn_mfma_f32_16x16x32_bf16(pa, vb, o, 0, 0, 0);
    }
    #pragma unroll
    for (int r = 0; r < 4; ++r)
        ctx[((size_t)b * L + i0 + quad * 4 + r) * D + h * DH + wave * 16 + fm] = f2bf(o[r]);
}

extern "C" void kernel_launch(void* const* d_in, const int* in_sizes, int n_in,
                              void* d_out, int out_size, void* d_ws, size_t ws_size,
                              hipStream_t stream) {
    const float* key_in   = (const float*)d_in[0];
    const float* value_in = (const float*)d_in[1];
    const float* query_in = (const float*)d_in[2];
    const int*   mat      = (const int*)d_in[3];
    const unsigned char* mask = (const unsigned char*)d_in[4];
    const float* Wq = (const float*)d_in[5];
    const float* bq = (const float*)d_in[6];
    const float* Wk = (const float*)d_in[7];
    const float* bk = (const float*)d_in[8];
    const float* Wv = (const float*)d_in[9];
    const float* bv = (const float*)d_in[10];
    const float* Wo = (const float*)d_in[11];
    const float* bo = (const float*)d_in[12];
    const float* struct_emb = (const float*)d_in[13];
    const float* value_emb  = (const float*)d_in[14];

    const int B = in_sizes[2] / (L * D);   // 4
    const int M = B * L;                   // 2048

    short* p = (short*)d_ws;
    short* xk  = p;  p += (size_t)M * D;
    short* xv  = p;  p += (size_t)M * D;
    short* xq  = p;  p += (size_t)M * D;
    short* WqT = p;  p += (size_t)D * D;
    short* WkT = p;  p += (size_t)D * D;
    short* WvT = p;  p += (size_t)D * D;
    short* WoT = p;  p += (size_t)D * D;
    short* semb = p; p += 16384;
    short* vemb = p; p += (size_t)in_sizes[14];
    short* Qb = p;   p += (size_t)M * D;
    short* Kb = p;   p += (size_t)M * D;
    short* Vt = p;   p += (size_t)M * D;
    short* Sast = p; p += (size_t)B * L * H * L;
    short* ctx = xk;   // xk is dead after the K projection; fused writes ctx later (stream-ordered)

    float* out_p  = (float*)d_out;
    float* attn_p = out_p + (size_t)M * D;

    CvtArgs ca;
    ca.src[0] = key_in;     ca.dst[0] = xk;   ca.n[0] = M * D;
    ca.src[1] = value_in;   ca.dst[1] = xv;   ca.n[1] = M * D;
    ca.src[2] = query_in;   ca.dst[2] = xq;   ca.n[2] = M * D;
    ca.src[3] = struct_emb; ca.dst[3] = semb; ca.n[3] = in_sizes[13];
    ca.src[4] = value_emb;  ca.dst[4] = vemb; ca.n[4] = in_sizes[14];
    cvt_kernel<<<dim3((M * D) / 2048, 5), 256, 0, stream>>>(ca);

    WtArgs wa;
    wa.W[0] = Wq; wa.W[1] = Wk; wa.W[2] = Wv; wa.W[3] = Wo;
    wa.T[0] = WqT; wa.T[1] = WkT; wa.T[2] = WvT; wa.T[3] = WoT;
    wtrans_kernel<<<dim3(512, 1, 4), 256, 0, stream>>>(wa);

    dim3 gg(D / BN, M / BM);   // (16, 16)
    gemm_bf16_kernel<<<gg, 256, 0, stream>>>(xq, WqT, bq, Qb, M, D, D, 0.125f, 1);
    gemm_bf16_kernel<<<gg, 256, 0, stream>>>(xk, WkT, bk, Kb, M, D, D, 1.0f, 1);
    gemm_bf16_kernel<<<gg, 256, 0, stream>>>(xv, WvT, bv, Vt, M, D, D, 1.0f, 2);

    ast_kernel<<<dim3(L, B), 256, 0, stream>>>(Qb, mat, semb, vemb, Sast);

    attn_fused_kernel<<<dim3(L / 16, H, B), 256, 0, stream>>>(
        Qb, Kb, Vt, Sast, mask, attn_p, ctx);

    gemm_bf16_kernel<<<gg, 256, 0, stream>>>(ctx, WoT, bo, out_p, M, D, D, 1.0f, 0);
}

// Round 4
// 242.002 us; speedup vs baseline: 8.7118x; 1.2147x over previous
//
#include <hip/hip_runtime.h>
#include <cstddef>

#define H 16
#define D 1024
#define DH 64
#define L 512

typedef __attribute__((ext_vector_type(8))) short bf16x8;
typedef __attribute__((ext_vector_type(4))) short bf16x4;
typedef __attribute__((ext_vector_type(4))) float f32x4;

__device__ inline short f2bf(float x) {
    union { float f; unsigned u; } c; c.f = x;
    unsigned r = (c.u + 0x7FFFu + ((c.u >> 16) & 1u)) >> 16;
    return (short)r;
}
__device__ inline float bf2f(short x) {
    union { float f; unsigned u; } c;
    c.u = ((unsigned)(unsigned short)x) << 16; return c.f;
}

__device__ inline void gload_lds16(const void* g, void* l) {
    __builtin_amdgcn_global_load_lds(
        (const __attribute__((address_space(1))) unsigned int*)g,
        (__attribute__((address_space(3))) unsigned int*)l,
        16, 0, 0);
}

// ---------------- fp32 -> bf16 convert (multi-region) ----------------
struct CvtArgs { const float* src[5]; short* dst[5]; int n[5]; };

__global__ __launch_bounds__(256) void cvt_kernel(CvtArgs a) {
    int r = blockIdx.y;
    const float* s = a.src[r];
    short* d = a.dst[r];
    int n = a.n[r];
    int i = (blockIdx.x * 256 + threadIdx.x) * 8;
    if (i >= n) return;
    float4 x0 = *(const float4*)(s + i);
    float4 x1 = *(const float4*)(s + i + 4);
    bf16x8 o;
    o[0] = f2bf(x0.x); o[1] = f2bf(x0.y); o[2] = f2bf(x0.z); o[3] = f2bf(x0.w);
    o[4] = f2bf(x1.x); o[5] = f2bf(x1.y); o[6] = f2bf(x1.z); o[7] = f2bf(x1.w);
    *(bf16x8*)(d + i) = o;
}

// ---------------- weight transpose+convert: W (K x N) fp32 -> W^T (N x K) bf16 ----------------
struct WtArgs { const float* W[4]; short* T[4]; };

__global__ __launch_bounds__(256) void wtrans_kernel(WtArgs a) {
    const float* W = a.W[blockIdx.z];
    short* T = a.T[blockIdx.z];
    int idx = blockIdx.x * 256 + threadIdx.x;
    int n = idx & 1023;
    int k0 = (idx >> 10) << 3;
    bf16x8 o;
    #pragma unroll
    for (int kk = 0; kk < 8; ++kk)
        o[kk] = f2bf(W[(size_t)(k0 + kk) * 1024 + n]);
    *(bf16x8*)(T + (size_t)n * 1024 + k0) = o;
}

// ---------------- MFMA GEMM, m97-style: global_load_lds + XOR-swizzled LDS ----------------
// C = (A @ Bt^T + bias) * scale.  A: (M,K) bf16 rm.  Bt: (N,K) bf16 rm.
// mode 0: fp32 flat [m][n]; mode 1: bf16 (B,H,L,DH); mode 2: bf16 (B,H,DH,L)
// LDS layout (no pad; DMA needs contiguity): 16-B unit at logical (row,u)
// stored at phys unit row*8 + (u ^ (row&7)).
#define BM 128
#define BN 64
#define BKK 64

struct GemmBatch {
    const short* A[3]; const short* Bt[3]; const float* bias[3];
    void* out[3]; float scale[3]; int mode[3];
};

__global__ __launch_bounds__(256) void gemm_mfma_kernel(GemmBatch P, int M, int N, int K) {
    const int z = blockIdx.z;
    const short* __restrict__ A  = P.A[z];
    const short* __restrict__ Bt = P.Bt[z];
    const float* __restrict__ bias = P.bias[z];
    const float scale = P.scale[z];
    const int mode = P.mode[z];

    __shared__ short lds[(BM + BN) * BKK];   // 24 KB
    short* As = lds;               // 128 x 64
    short* Bs = lds + BM * BKK;    // 64 x 64

    const int tid = threadIdx.x;
    const int wave = tid >> 6, lane = tid & 63;
    const int fm = lane & 15, quad = lane >> 4;
    const int m0 = blockIdx.y * BM, n0 = blockIdx.x * BN;

    // DMA source mapping: slot s hosts logical (row=s>>3, u=(s&7)^(row&7))
    int arow[4], acol[4];
    #pragma unroll
    for (int t = 0; t < 4; ++t) {
        int s = (wave * 4 + t) * 64 + lane;
        int row = s >> 3;
        int u = (s & 7) ^ (row & 7);
        arow[t] = row; acol[t] = u * 8;
    }
    int brow[2], bcol[2];
    #pragma unroll
    for (int t = 0; t < 2; ++t) {
        int s = (wave * 2 + t) * 64 + lane;
        int row = s >> 3;
        int u = (s & 7) ^ (row & 7);
        brow[t] = row; bcol[t] = u * 8;
    }

    // fragment read offsets (shorts)
    int aoff[2][2], boff[4][2];
    #pragma unroll
    for (int mt = 0; mt < 2; ++mt)
        #pragma unroll
        for (int kst = 0; kst < 2; ++kst) {
            int row = wave * 32 + mt * 16 + fm;
            int u = quad + 4 * kst;
            aoff[mt][kst] = row * 64 + ((u ^ (row & 7)) * 8);
        }
    #pragma unroll
    for (int nt = 0; nt < 4; ++nt)
        #pragma unroll
        for (int kst = 0; kst < 2; ++kst) {
            int row = nt * 16 + fm;
            int u = quad + 4 * kst;
            boff[nt][kst] = row * 64 + ((u ^ (row & 7)) * 8);
        }

    f32x4 acc[2][4];
    #pragma unroll
    for (int mt = 0; mt < 2; ++mt)
        #pragma unroll
        for (int nt = 0; nt < 4; ++nt) acc[mt][nt] = (f32x4){0.f, 0.f, 0.f, 0.f};

    for (int k0 = 0; k0 < K; k0 += BKK) {
        __syncthreads();   // prior iter's fragment reads complete
        #pragma unroll
        for (int t = 0; t < 4; ++t)
            gload_lds16(A + (size_t)(m0 + arow[t]) * K + k0 + acol[t],
                        As + (wave * 4 + t) * 512);
        #pragma unroll
        for (int t = 0; t < 2; ++t)
            gload_lds16(Bt + (size_t)(n0 + brow[t]) * K + k0 + bcol[t],
                        Bs + (wave * 2 + t) * 512);
        __syncthreads();   // drains vmcnt -> staged data visible
        #pragma unroll
        for (int kst = 0; kst < 2; ++kst) {
            bf16x8 af[2], bfr[4];
            af[0] = *(const bf16x8*)(As + aoff[0][kst]);
            af[1] = *(const bf16x8*)(As + aoff[1][kst]);
            #pragma unroll
            for (int nt = 0; nt < 4; ++nt)
                bfr[nt] = *(const bf16x8*)(Bs + boff[nt][kst]);
            #pragma unroll
            for (int mt = 0; mt < 2; ++mt)
                #pragma unroll
                for (int nt = 0; nt < 4; ++nt)
                    acc[mt][nt] = __builtin_amdgcn_mfma_f32_16x16x32_bf16(
                        af[mt], bfr[nt], acc[mt][nt], 0, 0, 0);
        }
    }

    if (mode == 2) {
        __syncthreads();
        short (*T)[BM + 8] = (short(*)[BM + 8])&lds[0];   // 64 x 136 = 17.4 KB <= 24 KB
        #pragma unroll
        for (int mt = 0; mt < 2; ++mt)
            #pragma unroll
            for (int nt = 0; nt < 4; ++nt) {
                int nn = nt * 16 + fm;
                float bv = bias[n0 + nn];
                #pragma unroll
                for (int r = 0; r < 4; ++r) {
                    int mm = wave * 32 + mt * 16 + quad * 4 + r;
                    T[nn][mm] = f2bf((acc[mt][nt][r] + bv) * scale);
                }
            }
        __syncthreads();
        int b = m0 >> 9;
        int ibase = m0 & (L - 1);
        int hblk = n0 >> 6;
        int n = tid >> 2, seg = (tid & 3) * 32;
        short* dst = (short*)P.out[z] + (((size_t)(b * H + hblk) * DH + n) * L) + ibase + seg;
        #pragma unroll
        for (int c = 0; c < 4; ++c)
            *(bf16x8*)(dst + c * 8) = *(const bf16x8*)(&T[n][seg + c * 8]);
    } else {
        #pragma unroll
        for (int mt = 0; mt < 2; ++mt)
            #pragma unroll
            for (int nt = 0; nt < 4; ++nt) {
                int n = n0 + nt * 16 + fm;
                float bv = bias[n];
                #pragma unroll
                for (int r = 0; r < 4; ++r) {
                    int m = m0 + wave * 32 + mt * 16 + quad * 4 + r;
                    float val = (acc[mt][nt][r] + bv) * scale;
                    if (mode == 0) {
                        ((float*)P.out[z])[(size_t)m * N + n] = val;
                    } else {
                        int b = m >> 9, i = m & (L - 1);
                        int h = n >> 6, d = n & (DH - 1);
                        ((short*)P.out[z])[(((size_t)(b * H + h) * L + i) * DH) + d] = f2bf(val);
                    }
                }
            }
    }
}

// ---------------- ast scores -> Sast bf16 [b][i][h][j] ----------------
__global__ __launch_bounds__(256) void ast_kernel(
    const short* __restrict__ Qb, const int* __restrict__ mat,
    const short* __restrict__ semb, const short* __restrict__ vemb,
    short* __restrict__ Sast)
{
    const int i = blockIdx.x, b = blockIdx.y;
    const int tid = threadIdx.x;
    const int wave = tid >> 6, lane = tid & 63;
    const int fm = lane & 15, quad = lane >> 4;
    __shared__ short Sl[H][L + 8];

    const short* qp = Qb + (((size_t)(b * H + fm) * L + i) * DH);
    bf16x8 a0 = *(const bf16x8*)(qp + quad * 8);
    bf16x8 a1 = *(const bf16x8*)(qp + 32 + quad * 8);

    const int* mrow = mat + ((size_t)b * L + i) * L;

    for (int jt = wave; jt < L / 16; jt += 4) {
        int j = jt * 16 + fm;
        int idx = mrow[j];
        const short* er = ((j & 1) ? vemb : semb) + (size_t)idx * DH;
        bf16x8 b0 = *(const bf16x8*)(er + quad * 8);
        bf16x8 b1 = *(const bf16x8*)(er + 32 + quad * 8);
        f32x4 c = {0.f, 0.f, 0.f, 0.f};
        c = __builtin_amdgcn_mfma_f32_16x16x32_bf16(a0, b0, c, 0, 0, 0);
        c = __builtin_amdgcn_mfma_f32_16x16x32_bf16(a1, b1, c, 0, 0, 0);
        #pragma unroll
        for (int r = 0; r < 4; ++r)
            Sl[quad * 4 + r][j] = f2bf(c[r]);
    }
    __syncthreads();
    int hh = tid >> 4, j0 = (tid & 15) * 32;
    short* dst = Sast + ((((size_t)b * L + i) * H + hh) * L) + j0;
    #pragma unroll
    for (int c = 0; c < 4; ++c)
        *(bf16x8*)(dst + c * 8) = *(const bf16x8*)(&Sl[hh][j0 + c * 8]);
}

// ---------------- fused qk + ast-add + softmax + PV (register scores) ----------------
// block = (i-tile of 16, h, b). Scores live in VGPRs (8 jt x 4 rows).
__global__ __launch_bounds__(256) void attn_fused_kernel(
    const short* __restrict__ Qb, const short* __restrict__ Kb,
    const short* __restrict__ Vt, const short* __restrict__ Sast,
    const unsigned char* __restrict__ mask,
    float* __restrict__ attn, short* __restrict__ ctx)
{
    const int i0 = blockIdx.x * 16;
    const int h = blockIdx.y;
    const int b = blockIdx.z;
    const int tid = threadIdx.x;
    const int wave = tid >> 6, lane = tid & 63;
    const int fm = lane & 15, quad = lane >> 4;

    __shared__ short Pb[16][L + 8];    // P bf16 for PV (16.6 KB)
    __shared__ float red_m[4][16];
    __shared__ float red_l[4][16];

    // Q fragment (A): rows i0+fm
    const short* qp = Qb + (((size_t)(b * H + h) * L + i0 + fm) * DH);
    bf16x8 a0 = *(const bf16x8*)(qp + quad * 8);
    bf16x8 a1 = *(const bf16x8*)(qp + 32 + quad * 8);
    const short* Kbase = Kb + ((size_t)(b * H + h) * L) * DH;
    const short* Sb = Sast + (((size_t)b * L + i0) * H + h) * L;

    float s[8][4];
    float mx[4] = {-3.0e38f, -3.0e38f, -3.0e38f, -3.0e38f};

    #pragma unroll
    for (int t = 0; t < 8; ++t) {
        int jt = wave + t * 4;
        int j = jt * 16 + fm;
        const short* kr = Kbase + (size_t)j * DH;
        bf16x8 b0 = *(const bf16x8*)(kr + quad * 8);
        bf16x8 b1 = *(const bf16x8*)(kr + 32 + quad * 8);
        f32x4 c = {0.f, 0.f, 0.f, 0.f};
        c = __builtin_amdgcn_mfma_f32_16x16x32_bf16(a0, b0, c, 0, 0, 0);
        c = __builtin_amdgcn_mfma_f32_16x16x32_bf16(a1, b1, c, 0, 0, 0);
        bool mk = mask[(size_t)b * L + j] != 0;
        #pragma unroll
        for (int r = 0; r < 4; ++r) {
            int ir = quad * 4 + r;
            float sv = c[r] + bf2f(Sb[(size_t)ir * H * L + j]);
            sv = mk ? -1e18f : sv;
            s[t][r] = sv;
            mx[r] = fmaxf(mx[r], sv);
        }
    }

    // row max: reduce across fm (within quad), then across waves via LDS
    #pragma unroll
    for (int off = 1; off <= 8; off <<= 1)
        #pragma unroll
        for (int r = 0; r < 4; ++r)
            mx[r] = fmaxf(mx[r], __shfl_xor(mx[r], off));
    if (fm == 0)
        #pragma unroll
        for (int r = 0; r < 4; ++r) red_m[wave][quad * 4 + r] = mx[r];
    __syncthreads();
    float M_[4];
    #pragma unroll
    for (int r = 0; r < 4; ++r) {
        int ir = quad * 4 + r;
        M_[r] = fmaxf(fmaxf(red_m[0][ir], red_m[1][ir]),
                      fmaxf(red_m[2][ir], red_m[3][ir]));
    }

    // exp + row sum
    float sum[4] = {0.f, 0.f, 0.f, 0.f};
    #pragma unroll
    for (int t = 0; t < 8; ++t)
        #pragma unroll
        for (int r = 0; r < 4; ++r) {
            float e = __expf(s[t][r] - M_[r]);
            s[t][r] = e;
            sum[r] += e;
        }
    #pragma unroll
    for (int off = 1; off <= 8; off <<= 1)
        #pragma unroll
        for (int r = 0; r < 4; ++r)
            sum[r] += __shfl_xor(sum[r], off);
    if (fm == 0)
        #pragma unroll
        for (int r = 0; r < 4; ++r) red_l[wave][quad * 4 + r] = sum[r];
    __syncthreads();
    float inv[4];
    #pragma unroll
    for (int r = 0; r < 4; ++r) {
        int ir = quad * 4 + r;
        inv[r] = 1.f / (red_l[0][ir] + red_l[1][ir] + red_l[2][ir] + red_l[3][ir]);
    }

    // normalize: write attn fp32 + Pb bf16
    #pragma unroll
    for (int t = 0; t < 8; ++t) {
        int j = (wave + t * 4) * 16 + fm;
        #pragma unroll
        for (int r = 0; r < 4; ++r) {
            int ir = quad * 4 + r;
            float p = s[t][r] * inv[r];
            attn[(((size_t)(b * H + h) * L + i0 + ir) * L) + j] = p;
            Pb[ir][j] = f2bf(p);
        }
    }
    __syncthreads();

    // PV via MFMA: wave owns d-tile [wave*16, wave*16+16)
    const short* Vb = Vt + (((size_t)(b * H + h) * DH + wave * 16 + fm) * L);
    f32x4 o = {0.f, 0.f, 0.f, 0.f};
    for (int ks = 0; ks < L; ks += 32) {
        bf16x8 pa = *(const bf16x8*)(&Pb[fm][ks + quad * 8]);
        bf16x8 vb = *(const bf16x8*)(Vb + ks + quad * 8);
        o = __builtin_amdgcn_mfma_f32_16x16x32_bf16(pa, vb, o, 0, 0, 0);
    }
    #pragma unroll
    for (int r = 0; r < 4; ++r)
        ctx[((size_t)b * L + i0 + quad * 4 + r) * D + h * DH + wave * 16 + fm] = f2bf(o[r]);
}

extern "C" void kernel_launch(void* const* d_in, const int* in_sizes, int n_in,
                              void* d_out, int out_size, void* d_ws, size_t ws_size,
                              hipStream_t stream) {
    const float* key_in   = (const float*)d_in[0];
    const float* value_in = (const float*)d_in[1];
    const float* query_in = (const float*)d_in[2];
    const int*   mat      = (const int*)d_in[3];
    const unsigned char* mask = (const unsigned char*)d_in[4];
    const float* Wq = (const float*)d_in[5];
    const float* bq = (const float*)d_in[6];
    const float* Wk = (const float*)d_in[7];
    const float* bk = (const float*)d_in[8];
    const float* Wv = (const float*)d_in[9];
    const float* bv = (const float*)d_in[10];
    const float* Wo = (const float*)d_in[11];
    const float* bo = (const float*)d_in[12];
    const float* struct_emb = (const float*)d_in[13];
    const float* value_emb  = (const float*)d_in[14];

    const int B = in_sizes[2] / (L * D);   // 4
    const int M = B * L;                   // 2048

    short* p = (short*)d_ws;
    short* xk  = p;  p += (size_t)M * D;
    short* xv  = p;  p += (size_t)M * D;
    short* xq  = p;  p += (size_t)M * D;
    short* WqT = p;  p += (size_t)D * D;
    short* WkT = p;  p += (size_t)D * D;
    short* WvT = p;  p += (size_t)D * D;
    short* WoT = p;  p += (size_t)D * D;
    short* semb = p; p += 16384;
    short* vemb = p; p += (size_t)in_sizes[14];
    short* Qb = p;   p += (size_t)M * D;
    short* Kb = p;   p += (size_t)M * D;
    short* Vt = p;   p += (size_t)M * D;
    short* Sast = p; p += (size_t)B * L * H * L;
    short* ctx = xk;   // dead after qkv projections; reused stream-ordered

    float* out_p  = (float*)d_out;
    float* attn_p = out_p + (size_t)M * D;

    CvtArgs ca;
    ca.src[0] = key_in;     ca.dst[0] = xk;   ca.n[0] = M * D;
    ca.src[1] = value_in;   ca.dst[1] = xv;   ca.n[1] = M * D;
    ca.src[2] = query_in;   ca.dst[2] = xq;   ca.n[2] = M * D;
    ca.src[3] = struct_emb; ca.dst[3] = semb; ca.n[3] = in_sizes[13];
    ca.src[4] = value_emb;  ca.dst[4] = vemb; ca.n[4] = in_sizes[14];
    cvt_kernel<<<dim3((M * D) / 2048, 5), 256, 0, stream>>>(ca);

    WtArgs wa;
    wa.W[0] = Wq; wa.W[1] = Wk; wa.W[2] = Wv; wa.W[3] = Wo;
    wa.T[0] = WqT; wa.T[1] = WkT; wa.T[2] = WvT; wa.T[3] = WoT;
    wtrans_kernel<<<dim3(512, 1, 4), 256, 0, stream>>>(wa);

    GemmBatch qkv;
    qkv.A[0] = xq; qkv.Bt[0] = WqT; qkv.bias[0] = bq; qkv.out[0] = Qb; qkv.scale[0] = 0.125f; qkv.mode[0] = 1;
    qkv.A[1] = xk; qkv.Bt[1] = WkT; qkv.bias[1] = bk; qkv.out[1] = Kb; qkv.scale[1] = 1.0f;   qkv.mode[1] = 1;
    qkv.A[2] = xv; qkv.Bt[2] = WvT; qkv.bias[2] = bv; qkv.out[2] = Vt; qkv.scale[2] = 1.0f;   qkv.mode[2] = 2;
    gemm_mfma_kernel<<<dim3(D / BN, M / BM, 3), 256, 0, stream>>>(qkv, M, D, D);

    ast_kernel<<<dim3(L, B), 256, 0, stream>>>(Qb, mat, semb, vemb, Sast);

    attn_fused_kernel<<<dim3(L / 16, H, B), 256, 0, stream>>>(
        Qb, Kb, Vt, Sast, mask, attn_p, ctx);

    GemmBatch fin;
    fin.A[0] = ctx; fin.Bt[0] = WoT; fin.bias[0] = bo; fin.out[0] = out_p; fin.scale[0] = 1.0f; fin.mode[0] = 0;
    fin.A[1] = ctx; fin.Bt[1] = WoT; fin.bias[1] = bo; fin.out[1] = out_p; fin.scale[1] = 1.0f; fin.mode[1] = 0;
    fin.A[2] = ctx; fin.Bt[2] = WoT; fin.bias[2] = bo; fin.out[2] = out_p; fin.scale[2] = 1.0f; fin.mode[2] = 0;
    gemm_mfma_kernel<<<dim3(D / BN, M / BM, 1), 256, 0, stream>>>(fin, M, D, D);
}